// Round 9
// baseline (130.923 us; speedup 1.0000x reference)
//
#include <hip/hip_runtime.h>
#include <math.h>

#define EPS  1e-6f
#define DD   256
#define NSUP 5
#define NQ   8
#define SEQ  13
#define L2E  1.44269504088896f
#define LN2  0.693147180559945f
#define NEP  2048            // episodes
#define NROW 16384           // NEP*NQ query rows
#define NCOL 2048            // anchor columns

typedef short bf16x8 __attribute__((ext_vector_type(8)));
typedef unsigned short u16x4 __attribute__((ext_vector_type(4)));
typedef float f32x4  __attribute__((ext_vector_type(4)));

__device__ __forceinline__ ushort f2bf(float f) {
  union { float f; unsigned u; } v; v.f = f;
  unsigned r = v.u + 0x7FFFu + ((v.u >> 16) & 1u);   // round-to-nearest-even
  return (ushort)(r >> 16);
}
__device__ __forceinline__ float bf2f(short u) {
  union { unsigned u; float f; } v; v.u = ((unsigned)(unsigned short)u) << 16;
  return v.f;
}

// ---------------------------------------------------------------------------
// prep (r8, proven): anchors/queries in MFMA-fragment-SWIZZLED order; element
// (c,d) -> ushort idx (((c>>4)*8+(d>>5))*64 + ((d>>3)&3)*16 + (c&15))*8+(d&7).
// cb[c] = -log2(e)*(sum(a^2) - 2*eps*sum(a)); row-constant cq cancels.
// ---------------------------------------------------------------------------
__global__ __launch_bounds__(256) void proto_prep(
    const float* __restrict__ x, float* __restrict__ cb,
    ushort* __restrict__ Asw, ushort* __restrict__ Qsw,
    float* __restrict__ accum, int* __restrict__ fincount) {
  const int tid = threadIdx.x, g = tid >> 6, l = tid & 63;
  const int n = blockIdx.x * 4 + g;
  if (blockIdx.x == 0 && tid == 0) { accum[0] = 0.f; accum[1] = 0.f; fincount[0] = 0; }

  const float4* xr4 = (const float4*)(x + (size_t)n * SEQ * DD);

  const int d0   = l * 4;
  const int kk   = d0 >> 5, quad = (d0 >> 3) & 3, j = d0 & 7;   // j in {0,4}
  const size_t chunk_d = (size_t)kk * 64 + (size_t)quad * 16;

  float4 a = {0.f, 0.f, 0.f, 0.f};
  #pragma unroll
  for (int s = 0; s < NSUP; ++s) {
    float4 v = xr4[s * 64 + l];
    a.x += v.x; a.y += v.y; a.z += v.z; a.w += v.w;
  }
  a.x *= 0.2f; a.y *= 0.2f; a.z *= 0.2f; a.w *= 0.2f;
  {
    const size_t idx = (((size_t)(n >> 4) * 8) * 64 + chunk_d + (n & 15)) * 8 + j;
    u16x4 o = {f2bf(a.x), f2bf(a.y), f2bf(a.z), f2bf(a.w)};
    *(u16x4*)(Asw + idx) = o;
  }
  float s1 = a.x + a.y + a.z + a.w;
  float s2 = a.x * a.x + a.y * a.y + a.z * a.z + a.w * a.w;
  #pragma unroll
  for (int off = 32; off; off >>= 1) {
    s1 += __shfl_xor(s1, off);
    s2 += __shfl_xor(s2, off);
  }
  if (l == 0) cb[n] = -L2E * (s2 - 2.f * EPS * s1);

  #pragma unroll
  for (int s = 0; s < NQ; ++s) {
    float4 q = xr4[(NSUP + s) * 64 + l];
    const int row = n * NQ + s;
    const size_t idx = (((size_t)(row >> 4) * 8) * 64 + chunk_d + (row & 15)) * 8 + j;
    u16x4 o = {f2bf(q.x), f2bf(q.y), f2bf(q.z), f2bf(q.w)};
    *(u16x4*)(Qsw + idx) = o;
  }
}

// ---------------------------------------------------------------------------
// main: 512 blocks x 256 threads; wave w owns col stripe [w*512,+512) = 32
// tiles of 16 cols. B tiles staged through PER-WAVE LDS double buffers via
// async global_load_lds (width 16) — no data VGPRs for staging (r4-r8's
// register ping-pong parked 64 VGPRs of bufs in AGPRs, capping residency at
// ~4 waves/CU). No __syncthreads in the K-loop (per-wave buffers); pipeline
// ordering via manual s_waitcnt vmcnt(8) (exactly 8 DMAs issued per iter,
// the only VMEM in the loop — cb comes from an LDS stripe staged up front)
// + sched_barrier(0) to pin ds_reads after the wait.
// LDS: 64 KB bufs + 8 KB cb + ~2 KB epilogue = ~74 KB -> 2 blocks/CU.
// MFMA layouts (verified): A m=lane&15,k=quad*8+j ; B n=lane&15,k=quad*8+j ;
// C col=lane&15,row=quad*4+reg.
// ---------------------------------------------------------------------------
__global__ __launch_bounds__(256, 2) void proto_main(
    const ushort* __restrict__ Qsw, const ushort* __restrict__ Asw,
    const float* __restrict__ cb, const int* __restrict__ label,
    float* __restrict__ accum, int* __restrict__ fincount,
    float* __restrict__ out) {
  const int tid  = threadIdx.x;
  const int wid  = tid >> 6, lane = tid & 63;
  const int quad = lane >> 4, lcol = lane & 15;
  const int r0   = blockIdx.x * 32;

  __shared__ __align__(16) ushort smem[4][2][4096];   // [wave][buf][8KB tile]
  __shared__ float scb[4][512];                       // per-wave cb stripe
  __shared__ float sm[4][32], ssh[4][32], slab[32];
  __shared__ int   sbi[4][32];

  const bf16x8* qb = (const bf16x8*)Qsw;
  const bf16x8* bb = (const bf16x8*)Asw;
  const int T0 = wid * 32;

  // stage this wave's cb stripe into LDS (keeps K-loop vmcnt stream pure DMA)
  #pragma unroll
  for (int i = 0; i < 8; ++i)
    scb[wid][i * 64 + lane] = cb[T0 * 16 + i * 64 + lane];

  // resident A fragments: 2 row-sets x 8 K-chunks (coalesced loads)
  bf16x8 af[2][8];
  #pragma unroll
  for (int set = 0; set < 2; ++set) {
    const size_t base = ((size_t)((r0 >> 4) + set) * 8) * 64 + lane;
    #pragma unroll
    for (int kk = 0; kk < 8; ++kk) af[set][kk] = qb[base + (size_t)kk * 64];
  }

  float m[2][4], s[2][4];
  int   bi[2][4];
  #pragma unroll
  for (int set = 0; set < 2; ++set)
    #pragma unroll
    for (int i = 0; i < 4; ++i) {
      m[set][i] = -1e30f; s[set][i] = 0.f; bi[set][i] = 0x7fffffff;
    }

  // async DMA of one 8 KB tile: 8 chunks, each 64 lanes x 16 B contiguous
  auto dma_tile = [&](int T, int bufi) {
    const ushort* src = Asw + ((size_t)T * 8) * 512 + (size_t)lane * 8;
    #pragma unroll
    for (int kk = 0; kk < 8; ++kk)
      __builtin_amdgcn_global_load_lds(
          (const __attribute__((address_space(1))) void*)(src + kk * 512),
          (__attribute__((address_space(3))) void*)(&smem[wid][bufi][kk * 512]),
          16, 0, 0);
  };

  dma_tile(T0, 0);                               // prologue: tile 0

  #pragma unroll 1
  for (int t = 0; t < 32; ++t) {
    const int Tn = (t + 1 < 32) ? T0 + t + 1 : T0 + t;   // tail: redundant DMA
    dma_tile(Tn, (t + 1) & 1);
    __builtin_amdgcn_s_waitcnt(0xF78);           // vmcnt(8): tile t resident
    __builtin_amdgcn_sched_barrier(0);           // pin ds_reads below the wait

    const ushort* B = &smem[wid][t & 1][0];
    f32x4 c0 = {0.f, 0.f, 0.f, 0.f}, c1 = {0.f, 0.f, 0.f, 0.f};
    #pragma unroll
    for (int kk = 0; kk < 8; ++kk) {
      bf16x8 b = *(const bf16x8*)(B + kk * 512 + lane * 8);
      c0 = __builtin_amdgcn_mfma_f32_16x16x32_bf16(af[0][kk], b, c0, 0, 0, 0);
      c1 = __builtin_amdgcn_mfma_f32_16x16x32_bf16(af[1][kk], b, c1, 0, 0, 0);
    }
    const int   colIdx = (T0 + t) * 16 + lcol;
    const float cbv    = scb[wid][t * 16 + lcol];   // LDS broadcast read
    #pragma unroll
    for (int set = 0; set < 2; ++set) {
      #pragma unroll
      for (int i = 0; i < 4; ++i) {
        float cv = (set == 0) ? c0[i] : c1[i];
        float v2 = fmaf(cv, 2.f * L2E, cbv);     // log2-frame shifted logit
        float dv = v2 - m[set][i];
        bool  gt = dv > 0.f;
        float e  = exp2f(-fabsf(dv));            // single non-unit exp factor
        s[set][i]  = fmaf(s[set][i], gt ? e : 1.f, gt ? 1.f : e);
        m[set][i]  = fmaxf(m[set][i], v2);
        bi[set][i] = gt ? colIdx : bi[set][i];   // strict >: first max wins
      }
    }
  }

  // merge across the 16 lanes sharing rows (cols differ)
  #pragma unroll
  for (int mask = 1; mask < 16; mask <<= 1) {
    #pragma unroll
    for (int set = 0; set < 2; ++set)
      #pragma unroll
      for (int i = 0; i < 4; ++i) {
        float om = __shfl_xor(m[set][i], mask);
        float os = __shfl_xor(s[set][i], mask);
        int   oi = __shfl_xor(bi[set][i], mask);
        float nm = fmaxf(m[set][i], om);
        s[set][i] = s[set][i] * exp2f(m[set][i] - nm) + os * exp2f(om - nm);
        bool better = (om > m[set][i]) || (om == m[set][i] && oi < bi[set][i]);
        bi[set][i] = better ? oi : bi[set][i];
        m[set][i]  = nm;
      }
  }

  if (lcol == 0) {
    #pragma unroll
    for (int set = 0; set < 2; ++set)
      #pragma unroll
      for (int i = 0; i < 4; ++i) {
        int rl = set * 16 + quad * 4 + i;
        sm[wid][rl] = m[set][i]; ssh[wid][rl] = s[set][i]; sbi[wid][rl] = bi[set][i];
      }
  }

  // label-logit post-pass (r6-r8 proven): 8 lanes per row, 32 rows; bf16 dot
  // with the same rounding as the MFMA path.
  {
    const int r = tid >> 3, l = tid & 7;
    const int row = r0 + r;
    const int lab = label[row >> 3];
    const size_t qbase = ((size_t)(row >> 4) * 8 + l) * 64 + (row & 15);
    const size_t abase = ((size_t)(lab >> 4) * 8 + l) * 64 + (lab & 15);
    float dot = 0.f;
    #pragma unroll
    for (int q16 = 0; q16 < 4; ++q16) {
      bf16x8 qv = qb[qbase + (size_t)q16 * 16];
      bf16x8 av = bb[abase + (size_t)q16 * 16];
      #pragma unroll
      for (int j = 0; j < 8; ++j) dot = fmaf(bf2f(qv[j]), bf2f(av[j]), dot);
    }
    #pragma unroll
    for (int mask = 1; mask < 8; mask <<= 1) dot += __shfl_xor(dot, mask);
    if (l == 0) slab[r] = fmaf(dot, 2.f * L2E, cb[lab]);  // shifted label logit
  }
  __syncthreads();

  if (tid < 32) {
    float mm = sm[0][tid], sv = ssh[0][tid];
    int   b  = sbi[0][tid];
    #pragma unroll
    for (int w = 1; w < 4; ++w) {            // stripes in ascending col order
      float om = sm[w][tid], os = ssh[w][tid];
      int   oi = sbi[w][tid];
      float nm = fmaxf(mm, om);
      sv = sv * exp2f(mm - nm) + os * exp2f(om - nm);
      bool better = (om > mm) || (om == mm && oi < b);
      b = better ? oi : b;
      mm = nm;
    }
    const int row = r0 + tid;
    const int lb  = label[row >> 3];
    float loss = LN2 * (mm + log2f(sv) - slab[tid]);
    float corr = (b == lb) ? 1.f : 0.f;
    #pragma unroll
    for (int mask = 16; mask; mask >>= 1) {   // xor stays closed in lanes 0..31
      loss += __shfl_xor(loss, mask);
      corr += __shfl_xor(corr, mask);
    }
    if (tid == 0) {
      atomicAdd(&accum[0], loss);
      atomicAdd(&accum[1], corr);
      __threadfence();
      if (atomicAdd(fincount, 1) == (int)gridDim.x - 1) {
        out[0] = atomicAdd(&accum[0], 0.f) / (float)NROW;   // coherent reads
        out[1] = atomicAdd(&accum[1], 0.f) * 100.f / (float)NROW;
      }
    }
  }
}

// ---------------------------------------------------------------------------
extern "C" void kernel_launch(void* const* d_in, const int* in_sizes, int n_in,
                              void* d_out, int out_size, void* d_ws, size_t ws_size,
                              hipStream_t stream) {
  const float* x     = (const float*)d_in[0];
  const int*   label = (const int*)d_in[1];
  float* out = (float*)d_out;

  // ws layout (float-sized slots): [0:2) accum | [2] fincount |
  // [16,16+NCOL) cb | Asw (NCOL*DD ushort) | Qsw (NROW*DD ushort)
  float*  W        = (float*)d_ws;
  float*  accum    = W;
  int*    fincount = (int*)(W + 2);
  float*  cb       = W + 16;
  ushort* Asw      = (ushort*)(cb + NCOL);
  ushort* Qsw      = Asw + (size_t)NCOL * DD;

  hipLaunchKernelGGL(proto_prep, dim3(NEP / 4), dim3(256), 0, stream,
                     x, cb, Asw, Qsw, accum, fincount);
  hipLaunchKernelGGL(proto_main, dim3(NROW / 32), dim3(256), 0, stream,
                     Qsw, Asw, cb, label, accum, fincount, out);
}

// Round 10
// 125.724 us; speedup vs baseline: 1.0414x; 1.0414x over previous
//
#include <hip/hip_runtime.h>
#include <math.h>

#define EPS  1e-6f
#define DD   256
#define NSUP 5
#define NQ   8
#define SEQ  13
#define L2E  1.44269504088896f
#define LN2  0.693147180559945f
#define NEP  2048            // episodes
#define NROW 16384           // NEP*NQ query rows
#define NCOL 2048            // anchor columns

typedef short bf16x8 __attribute__((ext_vector_type(8)));
typedef unsigned short u16x4 __attribute__((ext_vector_type(4)));
typedef float f32x4  __attribute__((ext_vector_type(4)));

__device__ __forceinline__ ushort f2bf(float f) {
  union { float f; unsigned u; } v; v.f = f;
  unsigned r = v.u + 0x7FFFu + ((v.u >> 16) & 1u);   // round-to-nearest-even
  return (ushort)(r >> 16);
}
__device__ __forceinline__ float bf2f(short u) {
  union { unsigned u; float f; } v; v.u = ((unsigned)(unsigned short)u) << 16;
  return v.f;
}

// ---------------------------------------------------------------------------
// prep (r8, proven): anchors/queries in MFMA-fragment-SWIZZLED order; element
// (c,d) -> ushort idx (((c>>4)*8+(d>>5))*64 + ((d>>3)&3)*16 + (c&15))*8+(d&7).
// cb[c] = -log2(e)*(sum(a^2) - 2*eps*sum(a)); row-constant cq cancels.
// ---------------------------------------------------------------------------
__global__ __launch_bounds__(256) void proto_prep(
    const float* __restrict__ x, float* __restrict__ cb,
    ushort* __restrict__ Asw, ushort* __restrict__ Qsw,
    float* __restrict__ accum, int* __restrict__ fincount) {
  const int tid = threadIdx.x, g = tid >> 6, l = tid & 63;
  const int n = blockIdx.x * 4 + g;
  if (blockIdx.x == 0 && tid == 0) { accum[0] = 0.f; accum[1] = 0.f; fincount[0] = 0; }

  const float4* xr4 = (const float4*)(x + (size_t)n * SEQ * DD);

  const int d0   = l * 4;
  const int kk   = d0 >> 5, quad = (d0 >> 3) & 3, j = d0 & 7;   // j in {0,4}
  const size_t chunk_d = (size_t)kk * 64 + (size_t)quad * 16;

  float4 a = {0.f, 0.f, 0.f, 0.f};
  #pragma unroll
  for (int s = 0; s < NSUP; ++s) {
    float4 v = xr4[s * 64 + l];
    a.x += v.x; a.y += v.y; a.z += v.z; a.w += v.w;
  }
  a.x *= 0.2f; a.y *= 0.2f; a.z *= 0.2f; a.w *= 0.2f;
  {
    const size_t idx = (((size_t)(n >> 4) * 8) * 64 + chunk_d + (n & 15)) * 8 + j;
    u16x4 o = {f2bf(a.x), f2bf(a.y), f2bf(a.z), f2bf(a.w)};
    *(u16x4*)(Asw + idx) = o;
  }
  float s1 = a.x + a.y + a.z + a.w;
  float s2 = a.x * a.x + a.y * a.y + a.z * a.z + a.w * a.w;
  #pragma unroll
  for (int off = 32; off; off >>= 1) {
    s1 += __shfl_xor(s1, off);
    s2 += __shfl_xor(s2, off);
  }
  if (l == 0) cb[n] = -L2E * (s2 - 2.f * EPS * s1);

  #pragma unroll
  for (int s = 0; s < NQ; ++s) {
    float4 q = xr4[(NSUP + s) * 64 + l];
    const int row = n * NQ + s;
    const size_t idx = (((size_t)(row >> 4) * 8) * 64 + chunk_d + (row & 15)) * 8 + j;
    u16x4 o = {f2bf(q.x), f2bf(q.y), f2bf(q.z), f2bf(q.w)};
    *(u16x4*)(Qsw + idx) = o;
  }
}

// ---------------------------------------------------------------------------
// main: r8's proven structure (512 blocks x 256 threads, wave w owns col
// stripe [w*512,+512) = 32 tiles, register ping-pong prefetch, 92 VGPR) with
// ONE change: per-block ROTATED tile order (T = T0 + ((t+rot)&31),
// rot = blockIdx*11 & 31). Theory: all blocks reading the same Asw lines in
// the same order serializes ~64 requesters/line per XCD L2 — the ~3.3k
// cyc/tile stall r4..r9 all share. Rotation spreads concurrent requests over
// ~32 distinct lines. Out-of-order column visits require a tie-aware in-loop
// argmax (v2==m -> lower colIdx wins) to preserve jnp.argmax semantics.
// MFMA layouts (verified): A m=lane&15,k=quad*8+j ; B n=lane&15,k=quad*8+j ;
// C col=lane&15,row=quad*4+reg.
// ---------------------------------------------------------------------------
__global__ __launch_bounds__(256, 2) void proto_main(
    const ushort* __restrict__ Qsw, const ushort* __restrict__ Asw,
    const float* __restrict__ cb, const int* __restrict__ label,
    float* __restrict__ accum, int* __restrict__ fincount,
    float* __restrict__ out) {
  const int tid  = threadIdx.x;
  const int wid  = tid >> 6, lane = tid & 63;
  const int quad = lane >> 4, lcol = lane & 15;
  const int r0   = blockIdx.x * 32;
  const int rot  = (blockIdx.x * 11) & 31;   // decorrelate L2 line streams

  const bf16x8* qb = (const bf16x8*)Qsw;
  const bf16x8* bb = (const bf16x8*)Asw;

  // resident A fragments: 2 row-sets x 8 K-chunks (coalesced loads)
  bf16x8 af[2][8];
  #pragma unroll
  for (int set = 0; set < 2; ++set) {
    const size_t base = ((size_t)((r0 >> 4) + set) * 8) * 64 + lane;
    #pragma unroll
    for (int kk = 0; kk < 8; ++kk) af[set][kk] = qb[base + (size_t)kk * 64];
  }

  float m[2][4], s[2][4];
  int   bi[2][4];
  #pragma unroll
  for (int set = 0; set < 2; ++set)
    #pragma unroll
    for (int i = 0; i < 4; ++i) {
      m[set][i] = -1e30f; s[set][i] = 0.f; bi[set][i] = 0x7fffffff;
    }

  auto process = [&](int T, bf16x8* B) {
    f32x4 c0 = {0.f, 0.f, 0.f, 0.f}, c1 = {0.f, 0.f, 0.f, 0.f};
    #pragma unroll
    for (int kk = 0; kk < 8; ++kk) {
      c0 = __builtin_amdgcn_mfma_f32_16x16x32_bf16(af[0][kk], B[kk], c0, 0, 0, 0);
      c1 = __builtin_amdgcn_mfma_f32_16x16x32_bf16(af[1][kk], B[kk], c1, 0, 0, 0);
    }
    const int   colIdx = T * 16 + lcol;
    const float cbv    = cb[colIdx];       // 64-B broadcast segment
    #pragma unroll
    for (int set = 0; set < 2; ++set) {
      #pragma unroll
      for (int i = 0; i < 4; ++i) {
        float cv = (set == 0) ? c0[i] : c1[i];
        float v2 = fmaf(cv, 2.f * L2E, cbv);     // log2-frame shifted logit
        float dv = v2 - m[set][i];
        bool  gt = dv > 0.f;
        float e  = exp2f(-fabsf(dv));            // single non-unit exp factor
        s[set][i]  = fmaf(s[set][i], gt ? e : 1.f, gt ? 1.f : e);
        // tie-aware argmax (cols visited out of order): lower index wins ties
        bool win = gt || (v2 == m[set][i] && colIdx < bi[set][i]);
        bi[set][i] = win ? colIdx : bi[set][i];
        m[set][i]  = fmaxf(m[set][i], v2);
      }
    }
  };

  const int T0 = wid * 32;
  bf16x8 buf0[8], buf1[8];
  #pragma unroll
  for (int kk = 0; kk < 8; ++kk)
    buf0[kk] = bb[((size_t)(T0 + rot) * 8 + (size_t)kk) * 64 + lane];

  #pragma unroll 1
  for (int t = 0; t < 32; t += 2) {
    {
      const int Tn = T0 + ((t + 1 + rot) & 31);
      #pragma unroll
      for (int kk = 0; kk < 8; ++kk)
        buf1[kk] = bb[((size_t)Tn * 8 + (size_t)kk) * 64 + lane];
    }
    process(T0 + ((t + rot) & 31), buf0);
    {
      const int Tm = T0 + ((t + 2 + rot) & 31);   // wraps at tail: redundant
      #pragma unroll
      for (int kk = 0; kk < 8; ++kk)
        buf0[kk] = bb[((size_t)Tm * 8 + (size_t)kk) * 64 + lane];
    }
    process(T0 + ((t + 1 + rot) & 31), buf1);
  }

  // merge across the 16 lanes sharing rows (cols differ)
  #pragma unroll
  for (int mask = 1; mask < 16; mask <<= 1) {
    #pragma unroll
    for (int set = 0; set < 2; ++set)
      #pragma unroll
      for (int i = 0; i < 4; ++i) {
        float om = __shfl_xor(m[set][i], mask);
        float os = __shfl_xor(s[set][i], mask);
        int   oi = __shfl_xor(bi[set][i], mask);
        float nm = fmaxf(m[set][i], om);
        s[set][i] = s[set][i] * exp2f(m[set][i] - nm) + os * exp2f(om - nm);
        bool better = (om > m[set][i]) || (om == m[set][i] && oi < bi[set][i]);
        bi[set][i] = better ? oi : bi[set][i];
        m[set][i]  = nm;
      }
  }

  __shared__ float sm[4][32], ssh[4][32], slab[32];
  __shared__ int   sbi[4][32];
  if (lcol == 0) {
    #pragma unroll
    for (int set = 0; set < 2; ++set)
      #pragma unroll
      for (int i = 0; i < 4; ++i) {
        int rl = set * 16 + quad * 4 + i;
        sm[wid][rl] = m[set][i]; ssh[wid][rl] = s[set][i]; sbi[wid][rl] = bi[set][i];
      }
  }

  // label-logit post-pass (r6-r8 proven): 8 lanes per row, 32 rows; bf16 dot
  // with the same rounding as the MFMA path.
  {
    const int r = tid >> 3, l = tid & 7;
    const int row = r0 + r;
    const int lab = label[row >> 3];
    const size_t qbase = ((size_t)(row >> 4) * 8 + l) * 64 + (row & 15);
    const size_t abase = ((size_t)(lab >> 4) * 8 + l) * 64 + (lab & 15);
    float dot = 0.f;
    #pragma unroll
    for (int q16 = 0; q16 < 4; ++q16) {
      bf16x8 qv = qb[qbase + (size_t)q16 * 16];
      bf16x8 av = bb[abase + (size_t)q16 * 16];
      #pragma unroll
      for (int j = 0; j < 8; ++j) dot = fmaf(bf2f(qv[j]), bf2f(av[j]), dot);
    }
    #pragma unroll
    for (int mask = 1; mask < 8; mask <<= 1) dot += __shfl_xor(dot, mask);
    if (l == 0) slab[r] = fmaf(dot, 2.f * L2E, cb[lab]);  // shifted label logit
  }
  __syncthreads();

  if (tid < 32) {
    float mm = sm[0][tid], sv = ssh[0][tid];
    int   b  = sbi[0][tid];
    #pragma unroll
    for (int w = 1; w < 4; ++w) {
      float om = sm[w][tid], os = ssh[w][tid];
      int   oi = sbi[w][tid];
      float nm = fmaxf(mm, om);
      sv = sv * exp2f(mm - nm) + os * exp2f(om - nm);
      bool better = (om > mm) || (om == mm && oi < b);
      b = better ? oi : b;
      mm = nm;
    }
    const int row = r0 + tid;
    const int lb  = label[row >> 3];
    float loss = LN2 * (mm + log2f(sv) - slab[tid]);
    float corr = (b == lb) ? 1.f : 0.f;
    #pragma unroll
    for (int mask = 16; mask; mask >>= 1) {   // xor stays closed in lanes 0..31
      loss += __shfl_xor(loss, mask);
      corr += __shfl_xor(corr, mask);
    }
    if (tid == 0) {
      atomicAdd(&accum[0], loss);
      atomicAdd(&accum[1], corr);
      __threadfence();
      if (atomicAdd(fincount, 1) == (int)gridDim.x - 1) {
        out[0] = atomicAdd(&accum[0], 0.f) / (float)NROW;   // coherent reads
        out[1] = atomicAdd(&accum[1], 0.f) * 100.f / (float)NROW;
      }
    }
  }
}

// ---------------------------------------------------------------------------
extern "C" void kernel_launch(void* const* d_in, const int* in_sizes, int n_in,
                              void* d_out, int out_size, void* d_ws, size_t ws_size,
                              hipStream_t stream) {
  const float* x     = (const float*)d_in[0];
  const int*   label = (const int*)d_in[1];
  float* out = (float*)d_out;

  // ws layout (float-sized slots): [0:2) accum | [2] fincount |
  // [16,16+NCOL) cb | Asw (NCOL*DD ushort) | Qsw (NROW*DD ushort)
  float*  W        = (float*)d_ws;
  float*  accum    = W;
  int*    fincount = (int*)(W + 2);
  float*  cb       = W + 16;
  ushort* Asw      = (ushort*)(cb + NCOL);
  ushort* Qsw      = Asw + (size_t)NCOL * DD;

  hipLaunchKernelGGL(proto_prep, dim3(NEP / 4), dim3(256), 0, stream,
                     x, cb, Asw, Qsw, accum, fincount);
  hipLaunchKernelGGL(proto_main, dim3(NROW / 32), dim3(256), 0, stream,
                     Qsw, Asw, cb, label, accum, fincount, out);
}